// Round 7
// baseline (430.457 us; speedup 1.0000x reference)
//
#include <hip/hip_runtime.h>

// MSDeformAttn encoder layer — bf16 MFMA GEMMs (global_load_lds staging,
// XCD-chunked block swizzle, fused dispatches, fused LN2 epilogue) +
// wave-per-query deformable sampling on a HEAD-MAJOR value tensor with a
// 2-deep gather pipeline (8 loads in flight -> L2 latency hidden).
#define DMODEL 256
#define NHEAD 8
#define NPOINT 4
#define NLEVEL 4
#define DHEAD 32
#define MLPD 1024
#define BSZ 2
#define LQTOK 21760
#define NTOK (BSZ * LQTOK)  // 43520
#define LNEPS 1e-6f

typedef __attribute__((ext_vector_type(8))) short short8;
typedef __attribute__((ext_vector_type(4))) float f32x4;
typedef __attribute__((ext_vector_type(2))) float f32x2;

__device__ __forceinline__ float bf2f(unsigned short u) {
  unsigned int i = ((unsigned int)u) << 16;
  return __builtin_bit_cast(float, i);
}
__device__ __forceinline__ unsigned short f2bf(float f) {
  unsigned int i = __builtin_bit_cast(unsigned int, f);
  i += 0x7fff + ((i >> 16) & 1);  // round-to-nearest-even
  return (unsigned short)(i >> 16);
}
__device__ __forceinline__ float bflo(unsigned int u) {
  return __builtin_bit_cast(float, u << 16);
}
__device__ __forceinline__ float bfhi(unsigned int u) {
  return __builtin_bit_cast(float, u & 0xffff0000u);
}

// d += a * b.lo / b.hi  (VOP3P packed f32 FMA; scalar broadcast via op_sel)
__device__ __forceinline__ void pk_fma_blo(f32x2& d, f32x2 a, f32x2 b) {
  asm("v_pk_fma_f32 %0, %1, %2, %0 op_sel:[0,0,0] op_sel_hi:[1,0,1]"
      : "+v"(d)
      : "v"(a), "v"(b));
}
__device__ __forceinline__ void pk_fma_bhi(f32x2& d, f32x2 a, f32x2 b) {
  asm("v_pk_fma_f32 %0, %1, %2, %0 op_sel:[0,1,0] op_sel_hi:[1,1,1]"
      : "+v"(d)
      : "v"(a), "v"(b));
}

// async global->LDS, 16B per lane; lds dest = wave-uniform base + lane*16
__device__ __forceinline__ void gload_lds16(const unsigned short* g,
                                            unsigned short* lds) {
  __builtin_amdgcn_global_load_lds(
      (const __attribute__((address_space(1))) unsigned int*)g,
      (__attribute__((address_space(3))) unsigned int*)lds, 16, 0, 0);
}

// bijective XCD-chunked block swizzle (m204): consecutive wgid stay on one
// XCD and iterate the column index fastest -> A-panel L2 reuse.
__device__ __forceinline__ unsigned xcd_swz(unsigned orig, unsigned nwg) {
  unsigned xcd = orig & 7u, rest = orig >> 3;
  unsigned qq = nwg >> 3, rr = nwg & 7u;
  return (xcd < rr ? xcd * (qq + 1) : rr * (qq + 1) + (xcd - rr) * qq) + rest;
}

// ---------------- layernorm: wave-per-row, no LDS/barriers -----------------
// o = bf16(LN(in)*g + beta); also q = bf16(bf2f(o) + pos)
__global__ __launch_bounds__(256) void ln_bf16(
    const float* __restrict__ in, const float* __restrict__ g,
    const float* __restrict__ beta, unsigned short* __restrict__ o,
    const float* __restrict__ pos, unsigned short* __restrict__ q) {
  const int w = threadIdx.x >> 6, lane = threadIdx.x & 63;
  const size_t t = (size_t)blockIdx.x * 4 + w;
  const size_t base = t * DMODEL + lane * 4;
  float4 v = *(const float4*)(in + base);
  float s = (v.x + v.y) + (v.z + v.w);
#pragma unroll
  for (int off = 32; off; off >>= 1) s += __shfl_xor(s, off, 64);
  float mu = s * (1.0f / DMODEL);
  float dx = v.x - mu, dy = v.y - mu, dz = v.z - mu, dw = v.w - mu;
  float s2 = (dx * dx + dy * dy) + (dz * dz + dw * dw);
#pragma unroll
  for (int off = 32; off; off >>= 1) s2 += __shfl_xor(s2, off, 64);
  float rs = rsqrtf(s2 * (1.0f / DMODEL) + LNEPS);
  float4 gg = *(const float4*)(g + lane * 4);
  float4 bb = *(const float4*)(beta + lane * 4);
  unsigned short r0 = f2bf(dx * rs * gg.x + bb.x);
  unsigned short r1 = f2bf(dy * rs * gg.y + bb.y);
  unsigned short r2 = f2bf(dz * rs * gg.z + bb.z);
  unsigned short r3 = f2bf(dw * rs * gg.w + bb.w);
  unsigned int lo = ((unsigned int)r1 << 16) | r0;
  unsigned int hi = ((unsigned int)r3 << 16) | r2;
  *(uint2*)(o + base) = make_uint2(lo, hi);
  float4 p = *(const float4*)(pos + base);
  unsigned short q0 = f2bf(bf2f(r0) + p.x);
  unsigned short q1 = f2bf(bf2f(r1) + p.y);
  unsigned short q2 = f2bf(bf2f(r2) + p.z);
  unsigned short q3 = f2bf(bf2f(r3) + p.w);
  unsigned int ql = ((unsigned int)q1 << 16) | q0;
  unsigned int qh = ((unsigned int)q3 << 16) | q2;
  *(uint2*)(q + base) = make_uint2(ql, qh);
}

// ------ all weight transposes in ONE dispatch: Wt[n][k] = bf16(W[k][n]) ----
__global__ __launch_bounds__(256) void transpose_all(
    const float* __restrict__ w_val, const float* __restrict__ w_off,
    const float* __restrict__ w_attn, const float* __restrict__ w_out,
    const float* __restrict__ w_fc1, const float* __restrict__ w_fc2,
    unsigned short* __restrict__ wvalT, unsigned short* __restrict__ woffaT,
    unsigned short* __restrict__ woutT, unsigned short* __restrict__ wfc1T,
    unsigned short* __restrict__ wfc2T) {
  __shared__ float tile[32][33];
  int bid = blockIdx.x;
  const float* W;
  unsigned short* Wt;
  int K, N, rel;
  if (bid < 64) {
    W = w_val; Wt = wvalT; K = 256; N = 256; rel = bid;
  } else if (bid < 128) {
    W = w_off; Wt = woffaT; K = 256; N = 256; rel = bid - 64;
  } else if (bid < 160) {
    W = w_attn; Wt = woffaT + 256 * 256; K = 256; N = 128; rel = bid - 128;
  } else if (bid < 224) {
    W = w_out; Wt = woutT; K = 256; N = 256; rel = bid - 160;
  } else if (bid < 480) {
    W = w_fc1; Wt = wfc1T; K = 256; N = 1024; rel = bid - 224;
  } else {
    W = w_fc2; Wt = wfc2T; K = 1024; N = 256; rel = bid - 480;
  }
  int ktiles = K >> 5;
  int k0 = (rel % ktiles) * 32, n0 = (rel / ktiles) * 32;
  int tx = threadIdx.x & 31, ty = threadIdx.x >> 5;  // 32 x 8
  for (int i = ty; i < 32; i += 8)
    tile[i][tx] = W[(size_t)(k0 + i) * N + n0 + tx];
  __syncthreads();
  for (int i = ty; i < 32; i += 8)
    Wt[(size_t)(n0 + i) * K + k0 + tx] = f2bf(tile[tx][i]);
}

// ---------------- bf16 MFMA GEMM core (m97 structure) ----------------------
// Tile 128x128, BK=32. OMODE: 2=bf16+relu, 3=f32+res.
template <int OMODE>
__global__ __launch_bounds__(256) void gemm_mfma(
    const unsigned short* __restrict__ A, const unsigned short* __restrict__ Wt,
    const float* __restrict__ bias, const float* __restrict__ res,
    void* __restrict__ Cout, int M, int N, int K) {
  __shared__ __attribute__((aligned(16))) unsigned short As[128 * 32];
  __shared__ __attribute__((aligned(16))) unsigned short Bs[128 * 32];
  const int tid = threadIdx.x;
  const unsigned gy = gridDim.y;
  const unsigned wgid = xcd_swz(blockIdx.y * gridDim.x + blockIdx.x,
                                gridDim.x * gy);
  const int m0 = (int)(wgid / gy) * 128;
  const int n0 = (int)(wgid % gy) * 128;
  const int wave = tid >> 6, lane = tid & 63;
  const int wm = (wave & 1) * 64, wn = (wave >> 1) * 64;
  const int lr = lane & 15, quad = lane >> 4;
  f32x4 acc[4][4] = {};
  for (int k0 = 0; k0 < K; k0 += 32) {
    __syncthreads();
#pragma unroll
    for (int r = 0; r < 2; r++) {
      int c = r * 256 + tid;
      int row = c >> 2, col8 = (c & 3) * 8;
      gload_lds16(Wt + (size_t)(n0 + row) * K + k0 + col8,
                  &Bs[(r * 256 + wave * 64) * 8]);
    }
#pragma unroll
    for (int r = 0; r < 2; r++) {
      int c = r * 256 + tid;
      int row = c >> 2, col8 = (c & 3) * 8;
      gload_lds16(A + (size_t)(m0 + row) * K + k0 + col8,
                  &As[(r * 256 + wave * 64) * 8]);
    }
    __syncthreads();
    short8 af[4], bfr[4];
#pragma unroll
    for (int i = 0; i < 4; i++)
      af[i] = *(const short8*)(&As[(wm + i * 16 + lr) * 32 + quad * 8]);
#pragma unroll
    for (int j = 0; j < 4; j++)
      bfr[j] = *(const short8*)(&Bs[(wn + j * 16 + lr) * 32 + quad * 8]);
#pragma unroll
    for (int i = 0; i < 4; i++)
#pragma unroll
      for (int j = 0; j < 4; j++)
        acc[i][j] = __builtin_amdgcn_mfma_f32_16x16x32_bf16(af[i], bfr[j],
                                                            acc[i][j], 0, 0, 0);
  }
#pragma unroll
  for (int i = 0; i < 4; i++) {
    int rbase = m0 + wm + i * 16 + quad * 4;
#pragma unroll
    for (int j = 0; j < 4; j++) {
      int col = n0 + wn + j * 16 + lr;
      float bv = bias[col];
#pragma unroll
      for (int r = 0; r < 4; r++) {
        size_t idx = (size_t)(rbase + r) * N + col;
        float v = acc[i][j][r] + bv;
        if (OMODE == 2) v = fmaxf(v, 0.0f);
        if (OMODE == 3) {
          ((float*)Cout)[idx] = v + res[idx];
        } else {
          ((unsigned short*)Cout)[idx] = f2bf(v);
        }
      }
    }
  }
}

// ---- fused val + off|attn GEMM: one dispatch, grid (340, 5) ----
// ny<2 -> val = x @ w_val (HEAD-MAJOR output [(b*8+h)][lq][32]);
// ny>=2 -> [off|logits] = q @ [w_off|w_attn].
__global__ __launch_bounds__(256) void gemm_vo(
    const unsigned short* __restrict__ Ax, const unsigned short* __restrict__ Aq,
    const unsigned short* __restrict__ Wval,
    const unsigned short* __restrict__ Woa, const float* __restrict__ bval,
    const float* __restrict__ boff, const float* __restrict__ battn,
    unsigned short* __restrict__ oval, unsigned short* __restrict__ ooff,
    unsigned short* __restrict__ olg) {
  __shared__ __attribute__((aligned(16))) unsigned short As[128 * 32];
  __shared__ __attribute__((aligned(16))) unsigned short Bs[128 * 32];
  const int tid = threadIdx.x;
  const unsigned gy = gridDim.y;  // 5
  const unsigned wgid = xcd_swz(blockIdx.y * gridDim.x + blockIdx.x,
                                gridDim.x * gy);
  const int m0 = (int)(wgid / gy) * 128;
  const int ny = (int)(wgid % gy);
  const bool isval = ny < 2;
  const unsigned short* A = isval ? Ax : Aq;
  const unsigned short* Wt = isval ? Wval : Woa;
  const int n0 = isval ? ny * 128 : (ny - 2) * 128;
  const int wave = tid >> 6, lane = tid & 63;
  const int wm = (wave & 1) * 64, wn = (wave >> 1) * 64;
  const int lr = lane & 15, quad = lane >> 4;
  f32x4 acc[4][4] = {};
  for (int k0 = 0; k0 < 256; k0 += 32) {
    __syncthreads();
#pragma unroll
    for (int r = 0; r < 2; r++) {
      int c = r * 256 + tid;
      int row = c >> 2, col8 = (c & 3) * 8;
      gload_lds16(Wt + (size_t)(n0 + row) * 256 + k0 + col8,
                  &Bs[(r * 256 + wave * 64) * 8]);
    }
#pragma unroll
    for (int r = 0; r < 2; r++) {
      int c = r * 256 + tid;
      int row = c >> 2, col8 = (c & 3) * 8;
      gload_lds16(A + (size_t)(m0 + row) * 256 + k0 + col8,
                  &As[(r * 256 + wave * 64) * 8]);
    }
    __syncthreads();
    short8 af[4], bfr[4];
#pragma unroll
    for (int i = 0; i < 4; i++)
      af[i] = *(const short8*)(&As[(wm + i * 16 + lr) * 32 + quad * 8]);
#pragma unroll
    for (int j = 0; j < 4; j++)
      bfr[j] = *(const short8*)(&Bs[(wn + j * 16 + lr) * 32 + quad * 8]);
#pragma unroll
    for (int i = 0; i < 4; i++)
#pragma unroll
      for (int j = 0; j < 4; j++)
        acc[i][j] = __builtin_amdgcn_mfma_f32_16x16x32_bf16(af[i], bfr[j],
                                                            acc[i][j], 0, 0, 0);
  }
#pragma unroll
  for (int i = 0; i < 4; i++) {
    int rbase = m0 + wm + i * 16 + quad * 4;
#pragma unroll
    for (int j = 0; j < 4; j++) {
      int col = n0 + wn + j * 16 + lr;
      float bv = isval ? bval[col]
                       : (col < 256 ? boff[col] : battn[col - 256]);
#pragma unroll
      for (int r = 0; r < 4; r++) {
        int row = rbase + r;
        float v = acc[i][j][r] + bv;
        if (isval) {
          int b_ = row >= LQTOK ? 1 : 0;
          int lq = row - b_ * LQTOK;
          int h = col >> 5, cc = col & 31;
          oval[(((size_t)b_ * 8 + h) * LQTOK + lq) * 32 + cc] = f2bf(v);
        } else if (col < 256) {
          ooff[(size_t)row * 256 + col] = f2bf(v);
        } else {
          olg[(size_t)row * 128 + (col - 256)] = f2bf(v);
        }
      }
    }
  }
}

// ---- out-projection GEMM with FUSED residual + LayerNorm epilogue ----
// Tile 128x256 (full row per block), 512 threads = 8 waves (2M x 4N),
// grid NTOK/128. Writes src2 (f32, for the fc2 residual) and
// y = LN(src2)*g2+beta2 (bf16) in one pass. var = E[x^2]-mu^2.
__global__ __launch_bounds__(512) void gemm_out_ln(
    const unsigned short* __restrict__ A, const unsigned short* __restrict__ Wt,
    const float* __restrict__ bias, const float* __restrict__ src,
    const float* __restrict__ g2, const float* __restrict__ beta2,
    float* __restrict__ src2, unsigned short* __restrict__ y) {
  __shared__ __attribute__((aligned(16))) unsigned short As[128 * 32];
  __shared__ __attribute__((aligned(16))) unsigned short Bs[256 * 32];
  __shared__ float red[2][128][4];
  const int tid = threadIdx.x;
  const int m0 = (int)blockIdx.x * 128;
  const int wave = tid >> 6, lane = tid & 63;
  const int wm = (wave & 1) * 64, wn = (wave >> 1) * 64;
  const int lr = lane & 15, quad = lane >> 4;
  f32x4 acc[4][4] = {};
  for (int k0 = 0; k0 < 256; k0 += 32) {
    __syncthreads();
    {
      int row = tid >> 2, col8 = (tid & 3) * 8;
      gload_lds16(A + (size_t)(m0 + row) * 256 + k0 + col8,
                  &As[(wave * 64) * 8]);
    }
#pragma unroll
    for (int r = 0; r < 2; r++) {
      int c = r * 512 + tid;
      int row = c >> 2, col8 = (c & 3) * 8;
      gload_lds16(Wt + (size_t)row * 256 + k0 + col8,
                  &Bs[((r * 8 + wave) * 64) * 8]);
    }
    __syncthreads();
    short8 af[4], bfr[4];
#pragma unroll
    for (int i = 0; i < 4; i++)
      af[i] = *(const short8*)(&As[(wm + i * 16 + lr) * 32 + quad * 8]);
#pragma unroll
    for (int j = 0; j < 4; j++)
      bfr[j] = *(const short8*)(&Bs[(wn + j * 16 + lr) * 32 + quad * 8]);
#pragma unroll
    for (int i = 0; i < 4; i++)
#pragma unroll
      for (int j = 0; j < 4; j++)
        acc[i][j] = __builtin_amdgcn_mfma_f32_16x16x32_bf16(af[i], bfr[j],
                                                            acc[i][j], 0, 0, 0);
  }
  // epilogue pass 1: src2 = acc + bias + src; accumulate row sums
  float s1[4][4] = {}, s2[4][4] = {};
#pragma unroll
  for (int i = 0; i < 4; i++)
#pragma unroll
    for (int j = 0; j < 4; j++) {
      int col = wn + j * 16 + lr;
      float bv = bias[col];
#pragma unroll
      for (int r = 0; r < 4; r++) {
        int row = m0 + wm + i * 16 + quad * 4 + r;
        size_t idx = (size_t)row * 256 + col;
        float v = acc[i][j][r] + bv + src[idx];
        src2[idx] = v;
        acc[i][j][r] = v;
        s1[i][r] += v;
        s2[i][r] = fmaf(v, v, s2[i][r]);
      }
    }
  // reduce over the 16 lr-lanes (stays within quad group)
#pragma unroll
  for (int i = 0; i < 4; i++)
#pragma unroll
    for (int r = 0; r < 4; r++)
#pragma unroll
      for (int s = 1; s < 16; s <<= 1) {
        s1[i][r] += __shfl_xor(s1[i][r], s, 64);
        s2[i][r] += __shfl_xor(s2[i][r], s, 64);
      }
  if (lr == 0) {
#pragma unroll
    for (int i = 0; i < 4; i++)
#pragma unroll
      for (int r = 0; r < 4; r++) {
        int rl = wm + i * 16 + quad * 4 + r;
        red[0][rl][wave >> 1] = s1[i][r];
        red[1][rl][wave >> 1] = s2[i][r];
      }
  }
  __syncthreads();
  // epilogue pass 2: y = (v - mu)*rs*g2 + beta2
#pragma unroll
  for (int i = 0; i < 4; i++)
#pragma unroll
    for (int r = 0; r < 4; r++) {
      int rl = wm + i * 16 + quad * 4 + r;
      float S1 = (red[0][rl][0] + red[0][rl][1]) +
                 (red[0][rl][2] + red[0][rl][3]);
      float S2 = (red[1][rl][0] + red[1][rl][1]) +
                 (red[1][rl][2] + red[1][rl][3]);
      float mu = S1 * (1.0f / DMODEL);
      float var = S2 * (1.0f / DMODEL) - mu * mu;
      float rs = rsqrtf(var + LNEPS);
      int row = m0 + rl;
#pragma unroll
      for (int j = 0; j < 4; j++) {
        int col = wn + j * 16 + lr;
        float yv = (acc[i][j][r] - mu) * rs * g2[col] + beta2[col];
        y[(size_t)row * 256 + col] = f2bf(yv);
      }
    }
}

// ---------------- deformable sampling + fused softmax ----------------
// Wave-per-query, 8 queries/block, NO __syncthreads. val is HEAD-MAJOR
// [(b*8+h)][token][32ch]; the (x, x+1) tap pair is 128B contiguous.
// Phase 2 runs a 2-DEEP LOAD PIPELINE over the 4 point-blocks: point-block
// pb+1's 8 dwordx4 gathers are issued before consuming pb (named A/B
// register sets, rule-#20 static indexing) -> 8 loads in flight per wave.
#define PREF_IDX(tt, wt, pb)                                        \
  _Pragma("unroll") for (int p = 0; p < 4; p++) {                   \
    int hs = h2 ^ (((pb)*4 + p) & 7);                               \
    tt[p] = sIdx[w][(pb)*4 + p][hs];                                \
    wt[p] = *(const f32x4*)sW[w][(pb)*4 + p][hs];                   \
  }
#define PREF_LD(v0, v1, tt)                                         \
  _Pragma("unroll") for (int p = 0; p < 4; p++) {                   \
    v0[p] = *(const uint4*)(base2 + (unsigned)tt[p].x);             \
    v1[p] = *(const uint4*)(base2 + (unsigned)tt[p].y);             \
  }
#define CONSUME(v0, v1, wt)                                         \
  _Pragma("unroll") for (int p = 0; p < 4; p++) {                   \
    f32x2 wp;                                                       \
    wp[0] = (g < 4) ? wt[p][0] : wt[p][1];                          \
    wp[1] = (g < 4) ? wt[p][2] : wt[p][3];                          \
    f32x2 u;                                                        \
    u[0] = bflo(v0[p].x); u[1] = bfhi(v0[p].x); pk_fma_blo(a4[0], u, wp); \
    u[0] = bflo(v0[p].y); u[1] = bfhi(v0[p].y); pk_fma_blo(a4[1], u, wp); \
    u[0] = bflo(v0[p].z); u[1] = bfhi(v0[p].z); pk_fma_blo(a4[2], u, wp); \
    u[0] = bflo(v0[p].w); u[1] = bfhi(v0[p].w); pk_fma_blo(a4[3], u, wp); \
    u[0] = bflo(v1[p].x); u[1] = bfhi(v1[p].x); pk_fma_bhi(a4[0], u, wp); \
    u[0] = bflo(v1[p].y); u[1] = bfhi(v1[p].y); pk_fma_bhi(a4[1], u, wp); \
    u[0] = bflo(v1[p].z); u[1] = bfhi(v1[p].z); pk_fma_bhi(a4[2], u, wp); \
    u[0] = bflo(v1[p].w); u[1] = bfhi(v1[p].w); pk_fma_bhi(a4[3], u, wp); \
  }

__global__ __launch_bounds__(512) void deform_sample(
    const unsigned short* __restrict__ val, const unsigned short* __restrict__ off,
    const unsigned short* __restrict__ logits, const float* __restrict__ refp,
    unsigned short* __restrict__ out) {
  __shared__ __attribute__((aligned(16))) int2 sIdx[8][16][8];
  __shared__ __attribute__((aligned(16))) float sW[8][16][8][4];
  const int w = threadIdx.x >> 6, lane = threadIdx.x & 63;
  const int bq = blockIdx.x * 8 + w;
  const int b = __builtin_amdgcn_readfirstlane(bq / LQTOK);
  {
    const int HW_[4] = {128, 64, 32, 16};
    const int LSI_[4] = {0, 16384, 20480, 21504};
    int u0 = 2 * lane;
    int h = u0 >> 4;
    int lvl = (u0 >> 2) & 3;
    int pt0 = u0 & 15;
    int HW = HW_[lvl];
    float2 rp = ((const float2*)refp)[(size_t)bq * 4 + lvl];
    uint2 ov = *(const uint2*)(off + (size_t)bq * 256 + 4 * lane);
    unsigned int lgu = *(const unsigned int*)(logits + (size_t)bq * 128 + 2 * lane);
    float lg0 = bflo(lgu), lg1 = bfhi(lgu);
    // fused softmax over this head's 16 logits (8 lanes x 2)
    float mx = fmaxf(lg0, lg1);
#pragma unroll
    for (int s = 1; s < 8; s <<= 1) mx = fmaxf(mx, __shfl_xor(mx, s, 64));
    float e0 = expf(lg0 - mx), e1 = expf(lg1 - mx);
    float es = e0 + e1;
#pragma unroll
    for (int s = 1; s < 8; s <<= 1) es += __shfl_xor(es, s, 64);
    float inv = 1.0f / es;
    float a01[2] = {e0 * inv, e1 * inv};
    unsigned int ovv[2] = {ov.x, ov.y};
#pragma unroll
    for (int c = 0; c < 2; c++) {
      float x = fmaf(rp.x, (float)HW, bflo(ovv[c])) - 0.5f;
      float y = fmaf(rp.y, (float)HW, bfhi(ovv[c])) - 0.5f;
      float xf = floorf(x), yf = floorf(y);
      int x0 = (int)xf, y0 = (int)yf;
      float lx = x - xf, ly = y - yf;
      int x0c = min(max(x0, 0), HW - 1);
      int x1c = min(max(x0 + 1, 0), HW - 1);
      int y0c = min(max(y0, 0), HW - 1);
      int y1c = min(max(y0 + 1, 0), HW - 1);
      float m0x = (x0 >= 0 && x0 < HW) ? 1.f : 0.f;
      float m1x = (x0 + 1 >= 0 && x0 + 1 < HW) ? 1.f : 0.f;
      float m0y = (y0 >= 0 && y0 < HW) ? 1.f : 0.f;
      float m1y = (y0 + 1 >= 0 && y0 + 1 < HW) ? 1.f : 0.f;
      float a = a01[c];
      float w00 = (1.f - lx) * (1.f - ly) * m0x * m0y * a;
      float w01 = lx * (1.f - ly) * m1x * m0y * a;
      float w10 = (1.f - lx) * ly * m0x * m1y * a;
      float w11 = lx * ly * m1x * m1y * a;
      int xb = min(max(x0, 0), HW - 2);
      bool c0 = (x0c == xb), c1 = (x1c == xb);
      float A0 = (c0 ? w00 : 0.f) + (c1 ? w01 : 0.f);
      float B0 = (c0 ? 0.f : w00) + (c1 ? 0.f : w01);
      float A1 = (c0 ? w10 : 0.f) + (c1 ? w11 : 0.f);
      float B1 = (c0 ? 0.f : w10) + (c1 ? 0.f : w11);
      int pt = pt0 + c;
      int hs = h ^ (pt & 7);
      sIdx[w][pt][hs] = make_int2((LSI_[lvl] + y0c * HW + xb) * 64,
                                  (LSI_[lvl] + y1c * HW + xb) * 64);
      *(float4*)sW[w][pt][hs] = make_float4(A0, B0, A1, B1);
    }
  }
  // wave-synchronous handoff: same wave wrote, same wave reads.
  __builtin_amdgcn_wave_barrier();
  const int h2 = lane >> 3, g = lane & 7;
  const char* base2 = (const char*)val +
                      ((size_t)(b * 8 + h2) * LQTOK) * 64 + g * 16;
  f32x2 a4[4] = {};
  int2 ttA[4], ttB[4];
  f32x4 wtA[4], wtB[4];
  uint4 v0A[4], v1A[4], v0B[4], v1B[4];
  PREF_IDX(ttA, wtA, 0);
  PREF_LD(v0A, v1A, ttA);
  PREF_IDX(ttB, wtB, 1);
  PREF_LD(v0B, v1B, ttB);
  CONSUME(v0A, v1A, wtA);
  PREF_IDX(ttA, wtA, 2);
  PREF_LD(v0A, v1A, ttA);
  CONSUME(v0B, v1B, wtB);
  PREF_IDX(ttB, wtB, 3);
  PREF_LD(v0B, v1B, ttB);
  CONSUME(v0A, v1A, wtA);
  CONSUME(v0B, v1B, wtB);
  // combine the two x-token halves (lanes g and g^4 hold the same channels)
#pragma unroll
  for (int qv = 0; qv < 4; qv++) {
    a4[qv][0] += __shfl_xor(a4[qv][0], 4, 64);
    a4[qv][1] += __shfl_xor(a4[qv][1], 4, 64);
  }
  if (g < 4) {
    uint4 o;
    o.x = ((unsigned)f2bf(a4[0][1]) << 16) | f2bf(a4[0][0]);
    o.y = ((unsigned)f2bf(a4[1][1]) << 16) | f2bf(a4[1][0]);
    o.z = ((unsigned)f2bf(a4[2][1]) << 16) | f2bf(a4[2][0]);
    o.w = ((unsigned)f2bf(a4[3][1]) << 16) | f2bf(a4[3][0]);
    *(uint4*)(out + (size_t)bq * 256 + h2 * 32 + g * 8) = o;
  }
}

// ---------------- launch ----------------
extern "C" void kernel_launch(void* const* d_in, const int* in_sizes, int n_in,
                              void* d_out, int out_size, void* d_ws,
                              size_t ws_size, hipStream_t stream) {
  const float* src    = (const float*)d_in[0];
  const float* pos    = (const float*)d_in[1];
  const float* refp   = (const float*)d_in[2];
  const float* g1     = (const float*)d_in[5];
  const float* beta1  = (const float*)d_in[6];
  const float* w_off  = (const float*)d_in[7];
  const float* b_off  = (const float*)d_in[8];
  const float* w_attn = (const float*)d_in[9];
  const float* b_attn = (const float*)d_in[10];
  const float* w_val  = (const float*)d_in[11];
  const float* b_val  = (const float*)d_in[12];
  const float* w_out  = (const float*)d_in[13];
  const float* b_out  = (const float*)d_in[14];
  const float* g2     = (const float*)d_in[15];
  const float* beta2  = (const float*)d_in[16];
  const float* w_fc1  = (const float*)d_in[17];
  const float* b_fc1  = (const float*)d_in[18];
  const float* w_fc2  = (const float*)d_in[19];
  const float* b_fc2  = (const float*)d_in[20];
  float* out = (float*)d_out;

  // Workspace layout (byte budget identical to the verified baseline):
  //  b1..b4 (4 x 22.28MB, contiguous) double as the full FFN hidden (89.1MB)
  //  b5 (44.6MB) holds logits bf16 then y bf16; src2 lives in d_out.
  const size_t NT = (size_t)NTOK;
  unsigned short* b1 = (unsigned short*)d_ws;  // x bf16 -> sampled -> hid
  unsigned short* b2 = b1 + NT * 256;          // val bf16 (head-major) -> hid
  unsigned short* b3 = b2 + NT * 256;          // off bf16          -> hid
  unsigned short* b4 = b3 + NT * 256;          // q bf16            -> hid
  unsigned short* b5 = b4 + NT * 256;          // logits bf16 -> y bf16
  unsigned short* wvalT  = b5 + NT * 512;      // [256][256]
  unsigned short* woffaT = wvalT + 256 * 256;  // [384][256] (off|attn merged)
  unsigned short* woutT  = woffaT + 384 * 256; // [256][256]
  unsigned short* wfc1T  = woutT + 256 * 256;  // [1024][256]
  unsigned short* wfc2T  = wfc1T + 1024 * 256; // [256][1024]

  unsigned short* qb  = b4;  // q = x+pos, bf16 [NT][256]
  unsigned short* lgb = b5;  // logits bf16 [NT][128]
  unsigned short* yb  = b5;  // y bf16 [NT][256] (after logits dead)
  unsigned short* hid = b1;  // FFN hidden bf16 [NT][1024] spans b1..b4

  const int MT = NTOK / 128;  // 340

  // 0. all weight transposes (f32 -> bf16, [K][N] -> [N][K]) in ONE dispatch
  transpose_all<<<736, 256, 0, stream>>>(w_val, w_off, w_attn, w_out, w_fc1,
                                         w_fc2, wvalT, woffaT, woutT, wfc1T,
                                         wfc2T);
  // 1. x = LN(src) -> b1 (bf16); q = bf16(x)+pos -> qb (bf16)
  ln_bf16<<<NTOK / 4, 256, 0, stream>>>(src, g1, beta1, b1, pos, qb);
  // 2. fused: val(head-major) = x @ w_val -> b2 ; [off|logits] = q @ woffa
  gemm_vo<<<dim3(MT, 5), 256, 0, stream>>>(b1, qb, wvalT, woffaT, b_val, b_off,
                                           b_attn, b2, b3, lgb);
  // 3. sampling (fused softmax) -> b1 (x dead, q dead)
  deform_sample<<<NTOK / 8, 512, 0, stream>>>(b2, b3, lgb, refp, b1);
  // 4. src2 = sampled @ w_out + b_out + src -> d_out (f32) AND
  //    y = LN(src2) -> yb (bf16), fused in one dispatch
  gemm_out_ln<<<MT, 512, 0, stream>>>(b1, woutT, b_out, src, g2, beta2,
                                      out, yb);
  // 5. hid = relu(y @ w_fc1 + b_fc1) -> b1..b4 (89.1MB, all dead)
  gemm_mfma<2><<<dim3(MT, 8), 256, 0, stream>>>(yb, wfc1T, b_fc1, nullptr, hid,
                                                NTOK, 1024, 256);
  // 6. out = hid @ w_fc2 + b_fc2 + src2(d_out) -> d_out (read-then-write)
  gemm_mfma<3><<<dim3(MT, 2), 256, 0, stream>>>(hid, wfc2T, b_fc2, out, out,
                                                NTOK, 256, 1024);
}

// Round 8
// 418.779 us; speedup vs baseline: 1.0279x; 1.0279x over previous
//
#include <hip/hip_runtime.h>

// MSDeformAttn encoder layer — bf16 MFMA GEMMs (global_load_lds staging,
// two-panel BK=64 barrier windows, XCD-chunked block swizzle, fused
// dispatches, fused LN2 epilogue) + wave-per-query deformable sampling on a
// HEAD-MAJOR value tensor (x-tap pairs contiguous -> dwordx4 gathers).
#define DMODEL 256
#define NHEAD 8
#define NPOINT 4
#define NLEVEL 4
#define DHEAD 32
#define MLPD 1024
#define BSZ 2
#define LQTOK 21760
#define NTOK (BSZ * LQTOK)  // 43520
#define LNEPS 1e-6f

typedef __attribute__((ext_vector_type(8))) short short8;
typedef __attribute__((ext_vector_type(4))) float f32x4;
typedef __attribute__((ext_vector_type(2))) float f32x2;

__device__ __forceinline__ float bf2f(unsigned short u) {
  unsigned int i = ((unsigned int)u) << 16;
  return __builtin_bit_cast(float, i);
}
__device__ __forceinline__ unsigned short f2bf(float f) {
  unsigned int i = __builtin_bit_cast(unsigned int, f);
  i += 0x7fff + ((i >> 16) & 1);  // round-to-nearest-even
  return (unsigned short)(i >> 16);
}
__device__ __forceinline__ float bflo(unsigned int u) {
  return __builtin_bit_cast(float, u << 16);
}
__device__ __forceinline__ float bfhi(unsigned int u) {
  return __builtin_bit_cast(float, u & 0xffff0000u);
}

// d += a * b.lo / b.hi  (VOP3P packed f32 FMA; scalar broadcast via op_sel)
__device__ __forceinline__ void pk_fma_blo(f32x2& d, f32x2 a, f32x2 b) {
  asm("v_pk_fma_f32 %0, %1, %2, %0 op_sel:[0,0,0] op_sel_hi:[1,0,1]"
      : "+v"(d)
      : "v"(a), "v"(b));
}
__device__ __forceinline__ void pk_fma_bhi(f32x2& d, f32x2 a, f32x2 b) {
  asm("v_pk_fma_f32 %0, %1, %2, %0 op_sel:[0,1,0] op_sel_hi:[1,1,1]"
      : "+v"(d)
      : "v"(a), "v"(b));
}

// async global->LDS, 16B per lane; lds dest = wave-uniform base + lane*16
__device__ __forceinline__ void gload_lds16(const unsigned short* g,
                                            unsigned short* lds) {
  __builtin_amdgcn_global_load_lds(
      (const __attribute__((address_space(1))) unsigned int*)g,
      (__attribute__((address_space(3))) unsigned int*)lds, 16, 0, 0);
}

// bijective XCD-chunked block swizzle (m204): consecutive wgid stay on one
// XCD and iterate the column index fastest -> A-panel L2 reuse.
__device__ __forceinline__ unsigned xcd_swz(unsigned orig, unsigned nwg) {
  unsigned xcd = orig & 7u, rest = orig >> 3;
  unsigned qq = nwg >> 3, rr = nwg & 7u;
  return (xcd < rr ? xcd * (qq + 1) : rr * (qq + 1) + (xcd - rr) * qq) + rest;
}

// ---------------- layernorm: wave-per-row, no LDS/barriers -----------------
// o = bf16(LN(in)*g + beta); also q = bf16(bf2f(o) + pos)
__global__ __launch_bounds__(256) void ln_bf16(
    const float* __restrict__ in, const float* __restrict__ g,
    const float* __restrict__ beta, unsigned short* __restrict__ o,
    const float* __restrict__ pos, unsigned short* __restrict__ q) {
  const int w = threadIdx.x >> 6, lane = threadIdx.x & 63;
  const size_t t = (size_t)blockIdx.x * 4 + w;
  const size_t base = t * DMODEL + lane * 4;
  float4 v = *(const float4*)(in + base);
  float s = (v.x + v.y) + (v.z + v.w);
#pragma unroll
  for (int off = 32; off; off >>= 1) s += __shfl_xor(s, off, 64);
  float mu = s * (1.0f / DMODEL);
  float dx = v.x - mu, dy = v.y - mu, dz = v.z - mu, dw = v.w - mu;
  float s2 = (dx * dx + dy * dy) + (dz * dz + dw * dw);
#pragma unroll
  for (int off = 32; off; off >>= 1) s2 += __shfl_xor(s2, off, 64);
  float rs = rsqrtf(s2 * (1.0f / DMODEL) + LNEPS);
  float4 gg = *(const float4*)(g + lane * 4);
  float4 bb = *(const float4*)(beta + lane * 4);
  unsigned short r0 = f2bf(dx * rs * gg.x + bb.x);
  unsigned short r1 = f2bf(dy * rs * gg.y + bb.y);
  unsigned short r2 = f2bf(dz * rs * gg.z + bb.z);
  unsigned short r3 = f2bf(dw * rs * gg.w + bb.w);
  unsigned int lo = ((unsigned int)r1 << 16) | r0;
  unsigned int hi = ((unsigned int)r3 << 16) | r2;
  *(uint2*)(o + base) = make_uint2(lo, hi);
  float4 p = *(const float4*)(pos + base);
  unsigned short q0 = f2bf(bf2f(r0) + p.x);
  unsigned short q1 = f2bf(bf2f(r1) + p.y);
  unsigned short q2 = f2bf(bf2f(r2) + p.z);
  unsigned short q3 = f2bf(bf2f(r3) + p.w);
  unsigned int ql = ((unsigned int)q1 << 16) | q0;
  unsigned int qh = ((unsigned int)q3 << 16) | q2;
  *(uint2*)(q + base) = make_uint2(ql, qh);
}

// ------ all weight transposes in ONE dispatch: Wt[n][k] = bf16(W[k][n]) ----
__global__ __launch_bounds__(256) void transpose_all(
    const float* __restrict__ w_val, const float* __restrict__ w_off,
    const float* __restrict__ w_attn, const float* __restrict__ w_out,
    const float* __restrict__ w_fc1, const float* __restrict__ w_fc2,
    unsigned short* __restrict__ wvalT, unsigned short* __restrict__ woffaT,
    unsigned short* __restrict__ woutT, unsigned short* __restrict__ wfc1T,
    unsigned short* __restrict__ wfc2T) {
  __shared__ float tile[32][33];
  int bid = blockIdx.x;
  const float* W;
  unsigned short* Wt;
  int K, N, rel;
  if (bid < 64) {
    W = w_val; Wt = wvalT; K = 256; N = 256; rel = bid;
  } else if (bid < 128) {
    W = w_off; Wt = woffaT; K = 256; N = 256; rel = bid - 64;
  } else if (bid < 160) {
    W = w_attn; Wt = woffaT + 256 * 256; K = 256; N = 128; rel = bid - 128;
  } else if (bid < 224) {
    W = w_out; Wt = woutT; K = 256; N = 256; rel = bid - 160;
  } else if (bid < 480) {
    W = w_fc1; Wt = wfc1T; K = 256; N = 1024; rel = bid - 224;
  } else {
    W = w_fc2; Wt = wfc2T; K = 1024; N = 256; rel = bid - 480;
  }
  int ktiles = K >> 5;
  int k0 = (rel % ktiles) * 32, n0 = (rel / ktiles) * 32;
  int tx = threadIdx.x & 31, ty = threadIdx.x >> 5;  // 32 x 8
  for (int i = ty; i < 32; i += 8)
    tile[i][tx] = W[(size_t)(k0 + i) * N + n0 + tx];
  __syncthreads();
  for (int i = ty; i < 32; i += 8)
    Wt[(size_t)(n0 + i) * K + k0 + tx] = f2bf(tile[tx][i]);
}

// ---------------- bf16 MFMA GEMM core -------------------------------------
// Tile 128x128, BK=64 as TWO m97-style 32-col panels per barrier window
// (identical LDS/bank pattern per panel, half the barriers vs BK=32).
// OMODE: 2=bf16+relu, 3=f32+res.
template <int OMODE>
__global__ __launch_bounds__(256) void gemm_mfma(
    const unsigned short* __restrict__ A, const unsigned short* __restrict__ Wt,
    const float* __restrict__ bias, const float* __restrict__ res,
    void* __restrict__ Cout, int M, int N, int K) {
  __shared__ __attribute__((aligned(16))) unsigned short As[2][128 * 32];
  __shared__ __attribute__((aligned(16))) unsigned short Bs[2][128 * 32];
  const int tid = threadIdx.x;
  const unsigned gy = gridDim.y;
  const unsigned wgid = xcd_swz(blockIdx.y * gridDim.x + blockIdx.x,
                                gridDim.x * gy);
  const int m0 = (int)(wgid / gy) * 128;
  const int n0 = (int)(wgid % gy) * 128;
  const int wave = tid >> 6, lane = tid & 63;
  const int wm = (wave & 1) * 64, wn = (wave >> 1) * 64;
  const int lr = lane & 15, quad = lane >> 4;
  const int srow = tid >> 2, scol8 = (tid & 3) * 8;      // staging row/col
  const int srow2 = (256 + tid) >> 2;
  f32x4 acc[4][4] = {};
  for (int k0 = 0; k0 < K; k0 += 64) {
    __syncthreads();
#pragma unroll
    for (int pp = 0; pp < 2; pp++) {
      int kb = k0 + pp * 32;
      gload_lds16(Wt + (size_t)(n0 + srow) * K + kb + scol8,
                  &Bs[pp][(wave * 64) * 8]);
      gload_lds16(Wt + (size_t)(n0 + srow2) * K + kb + scol8,
                  &Bs[pp][(256 + wave * 64) * 8]);
      gload_lds16(A + (size_t)(m0 + srow) * K + kb + scol8,
                  &As[pp][(wave * 64) * 8]);
      gload_lds16(A + (size_t)(m0 + srow2) * K + kb + scol8,
                  &As[pp][(256 + wave * 64) * 8]);
    }
    __syncthreads();
#pragma unroll
    for (int pp = 0; pp < 2; pp++) {
      short8 af[4], bfr[4];
#pragma unroll
      for (int i = 0; i < 4; i++)
        af[i] = *(const short8*)(&As[pp][(wm + i * 16 + lr) * 32 + quad * 8]);
#pragma unroll
      for (int j = 0; j < 4; j++)
        bfr[j] = *(const short8*)(&Bs[pp][(wn + j * 16 + lr) * 32 + quad * 8]);
#pragma unroll
      for (int i = 0; i < 4; i++)
#pragma unroll
        for (int j = 0; j < 4; j++)
          acc[i][j] = __builtin_amdgcn_mfma_f32_16x16x32_bf16(
              af[i], bfr[j], acc[i][j], 0, 0, 0);
    }
  }
#pragma unroll
  for (int i = 0; i < 4; i++) {
    int rbase = m0 + wm + i * 16 + quad * 4;
#pragma unroll
    for (int j = 0; j < 4; j++) {
      int col = n0 + wn + j * 16 + lr;
      float bv = bias[col];
#pragma unroll
      for (int r = 0; r < 4; r++) {
        size_t idx = (size_t)(rbase + r) * N + col;
        float v = acc[i][j][r] + bv;
        if (OMODE == 2) v = fmaxf(v, 0.0f);
        if (OMODE == 3) {
          ((float*)Cout)[idx] = v + res[idx];
        } else {
          ((unsigned short*)Cout)[idx] = f2bf(v);
        }
      }
    }
  }
}

// ---- fused val + off|attn GEMM: one dispatch, grid (340, 5) ----
// ny<2 -> val = x @ w_val (HEAD-MAJOR output [(b*8+h)][lq][32]);
// ny>=2 -> [off|logits] = q @ [w_off|w_attn]. Two-panel BK=64.
__global__ __launch_bounds__(256) void gemm_vo(
    const unsigned short* __restrict__ Ax, const unsigned short* __restrict__ Aq,
    const unsigned short* __restrict__ Wval,
    const unsigned short* __restrict__ Woa, const float* __restrict__ bval,
    const float* __restrict__ boff, const float* __restrict__ battn,
    unsigned short* __restrict__ oval, unsigned short* __restrict__ ooff,
    unsigned short* __restrict__ olg) {
  __shared__ __attribute__((aligned(16))) unsigned short As[2][128 * 32];
  __shared__ __attribute__((aligned(16))) unsigned short Bs[2][128 * 32];
  const int tid = threadIdx.x;
  const unsigned gy = gridDim.y;  // 5
  const unsigned wgid = xcd_swz(blockIdx.y * gridDim.x + blockIdx.x,
                                gridDim.x * gy);
  const int m0 = (int)(wgid / gy) * 128;
  const int ny = (int)(wgid % gy);
  const bool isval = ny < 2;
  const unsigned short* A = isval ? Ax : Aq;
  const unsigned short* Wt = isval ? Wval : Woa;
  const int n0 = isval ? ny * 128 : (ny - 2) * 128;
  const int wave = tid >> 6, lane = tid & 63;
  const int wm = (wave & 1) * 64, wn = (wave >> 1) * 64;
  const int lr = lane & 15, quad = lane >> 4;
  const int srow = tid >> 2, scol8 = (tid & 3) * 8;
  const int srow2 = (256 + tid) >> 2;
  f32x4 acc[4][4] = {};
  for (int k0 = 0; k0 < 256; k0 += 64) {
    __syncthreads();
#pragma unroll
    for (int pp = 0; pp < 2; pp++) {
      int kb = k0 + pp * 32;
      gload_lds16(Wt + (size_t)(n0 + srow) * 256 + kb + scol8,
                  &Bs[pp][(wave * 64) * 8]);
      gload_lds16(Wt + (size_t)(n0 + srow2) * 256 + kb + scol8,
                  &Bs[pp][(256 + wave * 64) * 8]);
      gload_lds16(A + (size_t)(m0 + srow) * 256 + kb + scol8,
                  &As[pp][(wave * 64) * 8]);
      gload_lds16(A + (size_t)(m0 + srow2) * 256 + kb + scol8,
                  &As[pp][(256 + wave * 64) * 8]);
    }
    __syncthreads();
#pragma unroll
    for (int pp = 0; pp < 2; pp++) {
      short8 af[4], bfr[4];
#pragma unroll
      for (int i = 0; i < 4; i++)
        af[i] = *(const short8*)(&As[pp][(wm + i * 16 + lr) * 32 + quad * 8]);
#pragma unroll
      for (int j = 0; j < 4; j++)
        bfr[j] = *(const short8*)(&Bs[pp][(wn + j * 16 + lr) * 32 + quad * 8]);
#pragma unroll
      for (int i = 0; i < 4; i++)
#pragma unroll
        for (int j = 0; j < 4; j++)
          acc[i][j] = __builtin_amdgcn_mfma_f32_16x16x32_bf16(
              af[i], bfr[j], acc[i][j], 0, 0, 0);
    }
  }
#pragma unroll
  for (int i = 0; i < 4; i++) {
    int rbase = m0 + wm + i * 16 + quad * 4;
#pragma unroll
    for (int j = 0; j < 4; j++) {
      int col = n0 + wn + j * 16 + lr;
      float bv = isval ? bval[col]
                       : (col < 256 ? boff[col] : battn[col - 256]);
#pragma unroll
      for (int r = 0; r < 4; r++) {
        int row = rbase + r;
        float v = acc[i][j][r] + bv;
        if (isval) {
          int b_ = row >= LQTOK ? 1 : 0;
          int lq = row - b_ * LQTOK;
          int h = col >> 5, cc = col & 31;
          oval[(((size_t)b_ * 8 + h) * LQTOK + lq) * 32 + cc] = f2bf(v);
        } else if (col < 256) {
          ooff[(size_t)row * 256 + col] = f2bf(v);
        } else {
          olg[(size_t)row * 128 + (col - 256)] = f2bf(v);
        }
      }
    }
  }
}

// ---- out-projection GEMM with FUSED residual + LayerNorm epilogue ----
// Tile 64x256 (full row per block), 256 threads, grid NTOK/64, two-panel
// BK=64. Writes src2 (f32) and y = LN(src2)*g2+beta2 (bf16) in one pass.
__global__ __launch_bounds__(256) void gemm_out_ln(
    const unsigned short* __restrict__ A, const unsigned short* __restrict__ Wt,
    const float* __restrict__ bias, const float* __restrict__ src,
    const float* __restrict__ g2, const float* __restrict__ beta2,
    float* __restrict__ src2, unsigned short* __restrict__ y) {
  __shared__ __attribute__((aligned(16))) unsigned short As[2][64 * 32];
  __shared__ __attribute__((aligned(16))) unsigned short Bs[2][256 * 32];
  __shared__ float red[2][64][2];
  const int tid = threadIdx.x;
  const int m0 = (int)blockIdx.x * 64;
  const int wave = tid >> 6, lane = tid & 63;
  const int wm = (wave >> 1) * 32, wn = (wave & 1) * 128;
  const int lr = lane & 15, quad = lane >> 4;
  const int srow = tid >> 2, scol8 = (tid & 3) * 8;
  f32x4 acc[2][8] = {};
  for (int k0 = 0; k0 < 256; k0 += 64) {
    __syncthreads();
#pragma unroll
    for (int pp = 0; pp < 2; pp++) {
      int kb = k0 + pp * 32;
      gload_lds16(A + (size_t)(m0 + srow) * 256 + kb + scol8,
                  &As[pp][(wave * 64) * 8]);
#pragma unroll
      for (int r = 0; r < 4; r++) {
        int c = r * 256 + tid;
        int row = c >> 2, col8 = (c & 3) * 8;
        gload_lds16(Wt + (size_t)row * 256 + kb + col8,
                    &Bs[pp][(r * 256 + wave * 64) * 8]);
      }
    }
    __syncthreads();
#pragma unroll
    for (int pp = 0; pp < 2; pp++) {
      short8 af[2], bfr[8];
#pragma unroll
      for (int i = 0; i < 2; i++)
        af[i] = *(const short8*)(&As[pp][(wm + i * 16 + lr) * 32 + quad * 8]);
#pragma unroll
      for (int j = 0; j < 8; j++)
        bfr[j] = *(const short8*)(&Bs[pp][(wn + j * 16 + lr) * 32 + quad * 8]);
#pragma unroll
      for (int i = 0; i < 2; i++)
#pragma unroll
        for (int j = 0; j < 8; j++)
          acc[i][j] = __builtin_amdgcn_mfma_f32_16x16x32_bf16(
              af[i], bfr[j], acc[i][j], 0, 0, 0);
    }
  }
  // epilogue pass 1: src2 = acc + bias + src; accumulate row sums
  float s1[2][4] = {}, s2[2][4] = {};
#pragma unroll
  for (int i = 0; i < 2; i++)
#pragma unroll
    for (int j = 0; j < 8; j++) {
      int col = wn + j * 16 + lr;
      float bv = bias[col];
#pragma unroll
      for (int r = 0; r < 4; r++) {
        int row = m0 + wm + i * 16 + quad * 4 + r;
        size_t idx = (size_t)row * 256 + col;
        float v = acc[i][j][r] + bv + src[idx];
        src2[idx] = v;
        acc[i][j][r] = v;
        s1[i][r] += v;
        s2[i][r] = fmaf(v, v, s2[i][r]);
      }
    }
  // reduce over the 16 lr-lanes
#pragma unroll
  for (int i = 0; i < 2; i++)
#pragma unroll
    for (int r = 0; r < 4; r++)
#pragma unroll
      for (int s = 1; s < 16; s <<= 1) {
        s1[i][r] += __shfl_xor(s1[i][r], s, 64);
        s2[i][r] += __shfl_xor(s2[i][r], s, 64);
      }
  if (lr == 0) {
#pragma unroll
    for (int i = 0; i < 2; i++)
#pragma unroll
      for (int r = 0; r < 4; r++) {
        int rl = wm + i * 16 + quad * 4 + r;
        red[0][rl][wave & 1] = s1[i][r];
        red[1][rl][wave & 1] = s2[i][r];
      }
  }
  __syncthreads();
  // epilogue pass 2: y = (v - mu)*rs*g2 + beta2
#pragma unroll
  for (int i = 0; i < 2; i++)
#pragma unroll
    for (int r = 0; r < 4; r++) {
      int rl = wm + i * 16 + quad * 4 + r;
      float S1 = red[0][rl][0] + red[0][rl][1];
      float S2 = red[1][rl][0] + red[1][rl][1];
      float mu = S1 * (1.0f / DMODEL);
      float var = S2 * (1.0f / DMODEL) - mu * mu;
      float rs = rsqrtf(var + LNEPS);
      int row = m0 + rl;
#pragma unroll
      for (int j = 0; j < 8; j++) {
        int col = wn + j * 16 + lr;
        float yv = (acc[i][j][r] - mu) * rs * g2[col] + beta2[col];
        y[(size_t)row * 256 + col] = f2bf(yv);
      }
    }
}

// ---------------- deformable sampling + fused softmax ----------------
// Wave-per-query, 8 queries/block, NO __syncthreads. val is HEAD-MAJOR
// [(b*8+h)][token][32ch]; the (x, x+1) tap pair is 128B contiguous.
// (round-6 verified version — the round-7 reg pipeline was compiler-sunk)
__global__ __launch_bounds__(512) void deform_sample(
    const unsigned short* __restrict__ val, const unsigned short* __restrict__ off,
    const unsigned short* __restrict__ logits, const float* __restrict__ refp,
    unsigned short* __restrict__ out) {
  __shared__ __attribute__((aligned(16))) int2 sIdx[8][16][8];
  __shared__ __attribute__((aligned(16))) float sW[8][16][8][4];
  const int w = threadIdx.x >> 6, lane = threadIdx.x & 63;
  const int bq = blockIdx.x * 8 + w;
  const int b = __builtin_amdgcn_readfirstlane(bq / LQTOK);
  {
    const int HW_[4] = {128, 64, 32, 16};
    const int LSI_[4] = {0, 16384, 20480, 21504};
    int u0 = 2 * lane;
    int h = u0 >> 4;
    int lvl = (u0 >> 2) & 3;
    int pt0 = u0 & 15;
    int HW = HW_[lvl];
    float2 rp = ((const float2*)refp)[(size_t)bq * 4 + lvl];
    uint2 ov = *(const uint2*)(off + (size_t)bq * 256 + 4 * lane);
    unsigned int lgu = *(const unsigned int*)(logits + (size_t)bq * 128 + 2 * lane);
    float lg0 = bflo(lgu), lg1 = bfhi(lgu);
    float mx = fmaxf(lg0, lg1);
#pragma unroll
    for (int s = 1; s < 8; s <<= 1) mx = fmaxf(mx, __shfl_xor(mx, s, 64));
    float e0 = expf(lg0 - mx), e1 = expf(lg1 - mx);
    float es = e0 + e1;
#pragma unroll
    for (int s = 1; s < 8; s <<= 1) es += __shfl_xor(es, s, 64);
    float inv = 1.0f / es;
    float a01[2] = {e0 * inv, e1 * inv};
    unsigned int ovv[2] = {ov.x, ov.y};
#pragma unroll
    for (int c = 0; c < 2; c++) {
      float x = fmaf(rp.x, (float)HW, bflo(ovv[c])) - 0.5f;
      float y = fmaf(rp.y, (float)HW, bfhi(ovv[c])) - 0.5f;
      float xf = floorf(x), yf = floorf(y);
      int x0 = (int)xf, y0 = (int)yf;
      float lx = x - xf, ly = y - yf;
      int x0c = min(max(x0, 0), HW - 1);
      int x1c = min(max(x0 + 1, 0), HW - 1);
      int y0c = min(max(y0, 0), HW - 1);
      int y1c = min(max(y0 + 1, 0), HW - 1);
      float m0x = (x0 >= 0 && x0 < HW) ? 1.f : 0.f;
      float m1x = (x0 + 1 >= 0 && x0 + 1 < HW) ? 1.f : 0.f;
      float m0y = (y0 >= 0 && y0 < HW) ? 1.f : 0.f;
      float m1y = (y0 + 1 >= 0 && y0 + 1 < HW) ? 1.f : 0.f;
      float a = a01[c];
      float w00 = (1.f - lx) * (1.f - ly) * m0x * m0y * a;
      float w01 = lx * (1.f - ly) * m1x * m0y * a;
      float w10 = (1.f - lx) * ly * m0x * m1y * a;
      float w11 = lx * ly * m1x * m1y * a;
      int xb = min(max(x0, 0), HW - 2);
      bool c0 = (x0c == xb), c1 = (x1c == xb);
      float A0 = (c0 ? w00 : 0.f) + (c1 ? w01 : 0.f);
      float B0 = (c0 ? 0.f : w00) + (c1 ? 0.f : w01);
      float A1 = (c0 ? w10 : 0.f) + (c1 ? w11 : 0.f);
      float B1 = (c0 ? 0.f : w10) + (c1 ? 0.f : w11);
      int pt = pt0 + c;
      int hs = h ^ (pt & 7);
      sIdx[w][pt][hs] = make_int2((LSI_[lvl] + y0c * HW + xb) * 64,
                                  (LSI_[lvl] + y1c * HW + xb) * 64);
      *(float4*)sW[w][pt][hs] = make_float4(A0, B0, A1, B1);
    }
  }
  __builtin_amdgcn_wave_barrier();
  const int h2 = lane >> 3, g = lane & 7;
  const char* base2 = (const char*)val +
                      ((size_t)(b * 8 + h2) * LQTOK) * 64 + g * 16;
  f32x2 a4[4] = {};
#pragma unroll
  for (int pb = 0; pb < 4; pb++) {
    int2 tt[4];
    f32x4 wt4[4];
#pragma unroll
    for (int p = 0; p < 4; p++) {
      int pt = pb * 4 + p;
      int hs = h2 ^ (pt & 7);
      tt[p] = sIdx[w][pt][hs];
      wt4[p] = *(const f32x4*)sW[w][pt][hs];
    }
    uint4 v0[4], v1[4];
#pragma unroll
    for (int p = 0; p < 4; p++) {
      v0[p] = *(const uint4*)(base2 + (unsigned)tt[p].x);
      v1[p] = *(const uint4*)(base2 + (unsigned)tt[p].y);
    }
#pragma unroll
    for (int p = 0; p < 4; p++) {
      f32x2 wp;
      wp[0] = (g < 4) ? wt4[p][0] : wt4[p][1];
      wp[1] = (g < 4) ? wt4[p][2] : wt4[p][3];
      f32x2 u;
      u[0] = bflo(v0[p].x); u[1] = bfhi(v0[p].x); pk_fma_blo(a4[0], u, wp);
      u[0] = bflo(v0[p].y); u[1] = bfhi(v0[p].y); pk_fma_blo(a4[1], u, wp);
      u[0] = bflo(v0[p].z); u[1] = bfhi(v0[p].z); pk_fma_blo(a4[2], u, wp);
      u[0] = bflo(v0[p].w); u[1] = bfhi(v0[p].w); pk_fma_blo(a4[3], u, wp);
      u[0] = bflo(v1[p].x); u[1] = bfhi(v1[p].x); pk_fma_bhi(a4[0], u, wp);
      u[0] = bflo(v1[p].y); u[1] = bfhi(v1[p].y); pk_fma_bhi(a4[1], u, wp);
      u[0] = bflo(v1[p].z); u[1] = bfhi(v1[p].z); pk_fma_bhi(a4[2], u, wp);
      u[0] = bflo(v1[p].w); u[1] = bfhi(v1[p].w); pk_fma_bhi(a4[3], u, wp);
    }
  }
#pragma unroll
  for (int qv = 0; qv < 4; qv++) {
    a4[qv][0] += __shfl_xor(a4[qv][0], 4, 64);
    a4[qv][1] += __shfl_xor(a4[qv][1], 4, 64);
  }
  if (g < 4) {
    uint4 o;
    o.x = ((unsigned)f2bf(a4[0][1]) << 16) | f2bf(a4[0][0]);
    o.y = ((unsigned)f2bf(a4[1][1]) << 16) | f2bf(a4[1][0]);
    o.z = ((unsigned)f2bf(a4[2][1]) << 16) | f2bf(a4[2][0]);
    o.w = ((unsigned)f2bf(a4[3][1]) << 16) | f2bf(a4[3][0]);
    *(uint4*)(out + (size_t)bq * 256 + h2 * 32 + g * 8) = o;
  }
}

// ---------------- launch ----------------
extern "C" void kernel_launch(void* const* d_in, const int* in_sizes, int n_in,
                              void* d_out, int out_size, void* d_ws,
                              size_t ws_size, hipStream_t stream) {
  const float* src    = (const float*)d_in[0];
  const float* pos    = (const float*)d_in[1];
  const float* refp   = (const float*)d_in[2];
  const float* g1     = (const float*)d_in[5];
  const float* beta1  = (const float*)d_in[6];
  const float* w_off  = (const float*)d_in[7];
  const float* b_off  = (const float*)d_in[8];
  const float* w_attn = (const float*)d_in[9];
  const float* b_attn = (const float*)d_in[10];
  const float* w_val  = (const float*)d_in[11];
  const float* b_val  = (const float*)d_in[12];
  const float* w_out  = (const float*)d_in[13];
  const float* b_out  = (const float*)d_in[14];
  const float* g2     = (const float*)d_in[15];
  const float* beta2  = (const float*)d_in[16];
  const float* w_fc1  = (const float*)d_in[17];
  const float* b_fc1  = (const float*)d_in[18];
  const float* w_fc2  = (const float*)d_in[19];
  const float* b_fc2  = (const float*)d_in[20];
  float* out = (float*)d_out;

  const size_t NT = (size_t)NTOK;
  unsigned short* b1 = (unsigned short*)d_ws;  // x bf16 -> sampled -> hid
  unsigned short* b2 = b1 + NT * 256;          // val bf16 (head-major) -> hid
  unsigned short* b3 = b2 + NT * 256;          // off bf16          -> hid
  unsigned short* b4 = b3 + NT * 256;          // q bf16            -> hid
  unsigned short* b5 = b4 + NT * 256;          // logits bf16 -> y bf16
  unsigned short* wvalT  = b5 + NT * 512;      // [256][256]
  unsigned short* woffaT = wvalT + 256 * 256;  // [384][256] (off|attn merged)
  unsigned short* woutT  = woffaT + 384 * 256; // [256][256]
  unsigned short* wfc1T  = woutT + 256 * 256;  // [1024][256]
  unsigned short* wfc2T  = wfc1T + 1024 * 256; // [256][1024]

  unsigned short* qb  = b4;  // q = x+pos, bf16 [NT][256]
  unsigned short* lgb = b5;  // logits bf16 [NT][128]
  unsigned short* yb  = b5;  // y bf16 [NT][256] (after logits dead)
  unsigned short* hid = b1;  // FFN hidden bf16 [NT][1024] spans b1..b4

  const int MT = NTOK / 128;  // 340

  // 0. all weight transposes (f32 -> bf16, [K][N] -> [N][K]) in ONE dispatch
  transpose_all<<<736, 256, 0, stream>>>(w_val, w_off, w_attn, w_out, w_fc1,
                                         w_fc2, wvalT, woffaT, woutT, wfc1T,
                                         wfc2T);
  // 1. x = LN(src) -> b1 (bf16); q = bf16(x)+pos -> qb (bf16)
  ln_bf16<<<NTOK / 4, 256, 0, stream>>>(src, g1, beta1, b1, pos, qb);
  // 2. fused: val(head-major) = x @ w_val -> b2 ; [off|logits] = q @ woffa
  gemm_vo<<<dim3(MT, 5), 256, 0, stream>>>(b1, qb, wvalT, woffaT, b_val, b_off,
                                           b_attn, b2, b3, lgb);
  // 3. sampling (fused softmax) -> b1 (x dead, q dead)
  deform_sample<<<NTOK / 8, 512, 0, stream>>>(b2, b3, lgb, refp, b1);
  // 4. src2 = sampled @ w_out + b_out + src -> d_out (f32) AND
  //    y = LN(src2) -> yb (bf16), fused in one dispatch
  gemm_out_ln<<<NTOK / 64, 256, 0, stream>>>(b1, woutT, b_out, src, g2, beta2,
                                             out, yb);
  // 5. hid = relu(y @ w_fc1 + b_fc1) -> b1..b4 (89.1MB, all dead)
  gemm_mfma<2><<<dim3(MT, 8), 256, 0, stream>>>(yb, wfc1T, b_fc1, nullptr, hid,
                                                NTOK, 1024, 256);
  // 6. out = hid @ w_fc2 + b_fc2 + src2(d_out) -> d_out (read-then-write)
  gemm_mfma<3><<<dim3(MT, 2), 256, 0, stream>>>(hid, wfc2T, b_fc2, out, out,
                                                NTOK, 256, 1024);
}